// Round 4
// baseline (383.221 us; speedup 1.0000x reference)
//
#include <hip/hip_runtime.h>
#include <math.h>

// Problem constants (from reference)
#define NPTS   65536        // 256*256
#define NB     5
#define NX     25
#define NY     7
#define NZ     6
#define NW     5
#define FG     (NB*NX*NY*NZ*NW)       // 26250 f_grid elements
#define GRID_ELEMS (2000 * FG)        // 52,500,000
// dst base (out+1+NPTS) is 4 mod 16 bytes -> elements e ≡ 3 (mod 4) start
// 16B-aligned dst chunks. Edges e = 0,1,2, GRID_ELEMS-1 handled separately.
#define NCHUNKM ((GRID_ELEMS - 4) / 4)   // 13,124,999 aligned-dst 16B chunks
#define CHUNKS_PER_BLOCK 1024            // 256 threads x 4 chunks
// out layout: [0]=loss, [1 .. 65536]=theta[0], [65537 ..]=grid_new
// ws layout: [0..4]=s[n], [5]=sum|theta|, [6]=sum(f*W4)

typedef float float4a __attribute__((ext_vector_type(4), aligned(4)));
typedef float float4v __attribute__((ext_vector_type(4), aligned(16)));

__device__ __forceinline__ float fgrid_eval(const float* s, int e2, float* w4out) {
    const float PI2 = 6.283185307179586f;
    const float dxs = PI2 / 24.0f;
    const float dys = 0.03f;          // 0.18/6
    const float dzs = 0.036f;         // 0.18/5
    const float dws = 0.05f;          // 0.2/4
    int d  = e2 % NW;
    int cz = (e2 / NW) % NZ;
    int b  = (e2 / (NW * NZ)) % NY;
    int a  = (e2 / (NW * NZ * NY)) % NX;
    int n  = e2 / (NW * NZ * NY * NX);
    float xv = PI2 * (float)a / 24.0f;
    float cv = cosf(xv);
    float yv = -0.09f + dys * (float)b;
    float zv = -0.09f + dzs * (float)cz;
    float wv = 0.9f  + dws * (float)d;
    float arg = s[n] * cv * wv + yv + zv;
    float f = expf(-arg * arg);
    *w4out = dxs * ((a == 0 || a == NX - 1) ? 0.5f : 1.0f)
           * dys * ((b == 0 || b == NY - 1) ? 0.5f : 1.0f)
           * dzs * ((cz == 0 || cz == NZ - 1) ? 0.5f : 1.0f)
           * dws * ((d == 0 || d == NW - 1) ? 0.5f : 1.0f);
    return f;
}

// Kernel A: s[n] = sum_i x[n,i]*theta[i], ws[5] = sum|theta|, theta passthrough.
__global__ void reduce_kernel(const float* __restrict__ x,
                              const float* __restrict__ theta,
                              float* __restrict__ out_theta,
                              float* __restrict__ ws) {
    __shared__ float smem[4 * 6];
    int idx = blockIdx.x * blockDim.x + threadIdx.x;   // 0..65535
    float t = theta[idx];
    out_theta[idx] = t;

    float vals[6];
#pragma unroll
    for (int n = 0; n < 5; ++n) vals[n] = x[n * NPTS + idx] * t;
    vals[5] = fabsf(t);

    int lane = threadIdx.x & 63;
    int wave = threadIdx.x >> 6;
#pragma unroll
    for (int k = 0; k < 6; ++k) {
        float v = vals[k];
#pragma unroll
        for (int off = 32; off > 0; off >>= 1) v += __shfl_down(v, off, 64);
        if (lane == 0) smem[wave * 6 + k] = v;
    }
    __syncthreads();
    if (threadIdx.x < 6) {
        float acc = smem[threadIdx.x] + smem[6 + threadIdx.x] +
                    smem[12 + threadIdx.x] + smem[18 + threadIdx.x];
        atomicAdd(&ws[threadIdx.x], acc);
    }
}

// Kernel B: pure streaming copy, 4 independent float4 pairs per thread.
// Block tile = 1024 chunks, thread handles chunks {base, base+256, ...} so
// each sub-pass stays fully coalesced. Slot j copied too (overwritten later).
__global__ void __launch_bounds__(256)
copy_kernel(const float* __restrict__ grid,
            float* __restrict__ out_grid) {     // out + 1 + NPTS
    const long long base = (long long)blockIdx.x * CHUNKS_PER_BLOCK + threadIdx.x;
    float4v v[4];
    long long c[4];
#pragma unroll
    for (int k = 0; k < 4; ++k) {
        c[k] = base + (long long)k * 256;
        if (c[k] < NCHUNKM) {
            float4a t = *(const float4a*)(grid + 3 + 4 * c[k]);  // src 12 mod 16
            v[k] = (float4v){t[0], t[1], t[2], t[3]};
        }
    }
#pragma unroll
    for (int k = 0; k < 4; ++k) {
        if (c[k] < NCHUNKM)
            __builtin_nontemporal_store(v[k], (float4v*)(out_grid + 3 + 4 * c[k]));
    }
    if (blockIdx.x == 0 && threadIdx.x == 0) {   // edge elements
        out_grid[0] = grid[0];
        out_grid[1] = grid[1];
        out_grid[2] = grid[2];
        out_grid[GRID_ELEMS - 1] = grid[GRID_ELEMS - 1];
    }
}

// Kernel C: overwrite slot j with f_grid (26250 elems) + loss partial sum.
__global__ void __launch_bounds__(256)
fgrid_kernel(const float* __restrict__ ws_in,
             float* __restrict__ ws_out,
             const int* __restrict__ jptr,
             float* __restrict__ out_grid) {    // out + 1 + NPTS
    __shared__ float smem[4];
    const int e = blockIdx.x * 256 + threadIdx.x;

    float s[5];
#pragma unroll
    for (int n = 0; n < 5; ++n) s[n] = ws_in[n];
    const int j = *jptr;

    float local = 0.0f;
    if (e < FG) {
        float w4;
        float f = fgrid_eval(s, e, &w4);
        out_grid[(long long)j * FG + e] = f;
        local = f * w4;
    }
#pragma unroll
    for (int off = 32; off > 0; off >>= 1) local += __shfl_down(local, off, 64);
    int lane = threadIdx.x & 63, wave = threadIdx.x >> 6;
    if (lane == 0) smem[wave] = local;
    __syncthreads();
    if (threadIdx.x == 0)
        atomicAdd(&ws_out[6], smem[0] + smem[1] + smem[2] + smem[3]);
}

// Kernel D: finalize loss
__global__ void finalize_kernel(const float* __restrict__ ws,
                                float* __restrict__ out) {
    out[0] = ws[6] - 0.5f * ws[5];
}

extern "C" void kernel_launch(void* const* d_in, const int* in_sizes, int n_in,
                              void* d_out, int out_size, void* d_ws, size_t ws_size,
                              hipStream_t stream) {
    const float* x     = (const float*)d_in[0];   // [5,256,256]
    const float* theta = (const float*)d_in[1];   // [1,256,256]
    const float* grid  = (const float*)d_in[2];   // [2000,5,25,7,6,5]
    const int*   jptr  = (const int*)d_in[3];     // scalar

    float* out = (float*)d_out;
    float* ws  = (float*)d_ws;

    hipMemsetAsync(ws, 0, 7 * sizeof(float), stream);

    reduce_kernel<<<NPTS / 256, 256, 0, stream>>>(x, theta, out + 1, ws);

    const int nblk = (NCHUNKM + CHUNKS_PER_BLOCK - 1) / CHUNKS_PER_BLOCK; // 12819
    copy_kernel<<<nblk, 256, 0, stream>>>(grid, out + 1 + NPTS);

    fgrid_kernel<<<(FG + 255) / 256, 256, 0, stream>>>(ws, ws, jptr,
                                                       out + 1 + NPTS);

    finalize_kernel<<<1, 1, 0, stream>>>(ws, out);
}

// Round 5
// 367.112 us; speedup vs baseline: 1.0439x; 1.0439x over previous
//
#include <hip/hip_runtime.h>
#include <math.h>

// Problem constants (from reference)
#define NPTS   65536        // 256*256
#define NB     5
#define NX     25
#define NY     7
#define NZ     6
#define NW     5
#define FG     (NB*NX*NY*NZ*NW)       // 26250 f_grid elements
#define GRID_ELEMS (2000 * FG)        // 52,500,000
// out layout: [0]=loss, [1 .. 65536]=theta[0], [65537 ..]=grid_new
// ws layout: [0..4]=s[n], [5]=sum|theta|, [6]=sum(f*W4)
//
// dst base (out+65537 floats) is 4 mod 16 bytes: NO access width >4B can be
// aligned on both src and dst. Therefore the copy uses pure dword accesses —
// both sides perfectly coalesced, no split transactions, no edge cases.

#define COPY_TPB   256
#define COPY_EPT   16                       // dwords per thread
#define COPY_TILE  (COPY_TPB * COPY_EPT)    // 4096 dwords per block

__device__ __forceinline__ float fgrid_eval(const float* s, int e2, float* w4out) {
    const float PI2 = 6.283185307179586f;
    const float dxs = PI2 / 24.0f;
    const float dys = 0.03f;          // 0.18/6
    const float dzs = 0.036f;         // 0.18/5
    const float dws = 0.05f;          // 0.2/4
    int d  = e2 % NW;
    int cz = (e2 / NW) % NZ;
    int b  = (e2 / (NW * NZ)) % NY;
    int a  = (e2 / (NW * NZ * NY)) % NX;
    int n  = e2 / (NW * NZ * NY * NX);
    float xv = PI2 * (float)a / 24.0f;
    float cv = cosf(xv);
    float yv = -0.09f + dys * (float)b;
    float zv = -0.09f + dzs * (float)cz;
    float wv = 0.9f  + dws * (float)d;
    float arg = s[n] * cv * wv + yv + zv;
    float f = expf(-arg * arg);
    *w4out = dxs * ((a == 0 || a == NX - 1) ? 0.5f : 1.0f)
           * dys * ((b == 0 || b == NY - 1) ? 0.5f : 1.0f)
           * dzs * ((cz == 0 || cz == NZ - 1) ? 0.5f : 1.0f)
           * dws * ((d == 0 || d == NW - 1) ? 0.5f : 1.0f);
    return f;
}

// Kernel A: s[n] = sum_i x[n,i]*theta[i], ws[5] = sum|theta|, theta passthrough.
__global__ void reduce_kernel(const float* __restrict__ x,
                              const float* __restrict__ theta,
                              float* __restrict__ out_theta,
                              float* __restrict__ ws) {
    __shared__ float smem[4 * 6];
    int idx = blockIdx.x * blockDim.x + threadIdx.x;   // 0..65535
    float t = theta[idx];
    out_theta[idx] = t;

    float vals[6];
#pragma unroll
    for (int n = 0; n < 5; ++n) vals[n] = x[n * NPTS + idx] * t;
    vals[5] = fabsf(t);

    int lane = threadIdx.x & 63;
    int wave = threadIdx.x >> 6;
#pragma unroll
    for (int k = 0; k < 6; ++k) {
        float v = vals[k];
#pragma unroll
        for (int off = 32; off > 0; off >>= 1) v += __shfl_down(v, off, 64);
        if (lane == 0) smem[wave * 6 + k] = v;
    }
    __syncthreads();
    if (threadIdx.x < 6) {
        float acc = smem[threadIdx.x] + smem[6 + threadIdx.x] +
                    smem[12 + threadIdx.x] + smem[18 + threadIdx.x];
        atomicAdd(&ws[threadIdx.x], acc);
    }
}

// Kernel B: pure dword streaming copy. Block tile = 4096 dwords; thread t
// copies dwords {tile + k*256 + t}, so every wave sub-pass is a contiguous
// 256B segment on BOTH src and dst (both 4B-aligned, zero splits).
// 16 loads issued back-to-back before the 16 stores -> deep MLP.
__global__ void __launch_bounds__(COPY_TPB)
copy_kernel(const float* __restrict__ src,
            float* __restrict__ dst) {          // dst = out + 1 + NPTS
    const int base = blockIdx.x * COPY_TILE + threadIdx.x;
    if (base + (COPY_EPT - 1) * COPY_TPB < GRID_ELEMS) {   // fast path
        float v[COPY_EPT];
#pragma unroll
        for (int k = 0; k < COPY_EPT; ++k) v[k] = src[base + k * COPY_TPB];
#pragma unroll
        for (int k = 0; k < COPY_EPT; ++k) dst[base + k * COPY_TPB] = v[k];
    } else {                                               // tail block
#pragma unroll
        for (int k = 0; k < COPY_EPT; ++k) {
            int e = base + k * COPY_TPB;
            if (e < GRID_ELEMS) dst[e] = src[e];
        }
    }
}

// Kernel C: overwrite slot j with f_grid (26250 elems) + loss partial sum.
__global__ void __launch_bounds__(256)
fgrid_kernel(const float* __restrict__ ws_in,
             float* __restrict__ ws_out,
             const int* __restrict__ jptr,
             float* __restrict__ out_grid) {    // out + 1 + NPTS
    __shared__ float smem[4];
    const int e = blockIdx.x * 256 + threadIdx.x;

    float s[5];
#pragma unroll
    for (int n = 0; n < 5; ++n) s[n] = ws_in[n];
    const int j = *jptr;

    float local = 0.0f;
    if (e < FG) {
        float w4;
        float f = fgrid_eval(s, e, &w4);
        out_grid[j * FG + e] = f;
        local = f * w4;
    }
#pragma unroll
    for (int off = 32; off > 0; off >>= 1) local += __shfl_down(local, off, 64);
    int lane = threadIdx.x & 63, wave = threadIdx.x >> 6;
    if (lane == 0) smem[wave] = local;
    __syncthreads();
    if (threadIdx.x == 0)
        atomicAdd(&ws_out[6], smem[0] + smem[1] + smem[2] + smem[3]);
}

// Kernel D: finalize loss
__global__ void finalize_kernel(const float* __restrict__ ws,
                                float* __restrict__ out) {
    out[0] = ws[6] - 0.5f * ws[5];
}

extern "C" void kernel_launch(void* const* d_in, const int* in_sizes, int n_in,
                              void* d_out, int out_size, void* d_ws, size_t ws_size,
                              hipStream_t stream) {
    const float* x     = (const float*)d_in[0];   // [5,256,256]
    const float* theta = (const float*)d_in[1];   // [1,256,256]
    const float* grid  = (const float*)d_in[2];   // [2000,5,25,7,6,5]
    const int*   jptr  = (const int*)d_in[3];     // scalar

    float* out = (float*)d_out;
    float* ws  = (float*)d_ws;

    hipMemsetAsync(ws, 0, 7 * sizeof(float), stream);

    reduce_kernel<<<NPTS / 256, 256, 0, stream>>>(x, theta, out + 1, ws);

    const int nblk = (GRID_ELEMS + COPY_TILE - 1) / COPY_TILE;   // 12818
    copy_kernel<<<nblk, COPY_TPB, 0, stream>>>(grid, out + 1 + NPTS);

    fgrid_kernel<<<(FG + 255) / 256, 256, 0, stream>>>(ws, ws, jptr,
                                                       out + 1 + NPTS);

    finalize_kernel<<<1, 1, 0, stream>>>(ws, out);
}